// Round 14
// baseline (5080.374 us; speedup 1.0000x reference)
//
#include <hip/hip_runtime.h>
#include <stdint.h>

#define TT 512
#define NSLOT 8

typedef __fp16   f16x8  __attribute__((ext_vector_type(8)));
typedef float    f32x4  __attribute__((ext_vector_type(4)));
typedef __fp16   fp16x2 __attribute__((ext_vector_type(2)));
typedef uint32_t u32x2  __attribute__((ext_vector_type(2)));
typedef unsigned long long ull;

__device__ __forceinline__ f32x4 mfma16(f16x8 a, f16x8 b, f32x4 c) {
    return __builtin_amdgcn_mfma_f32_16x16x32_f16(a, b, c, 0, 0, 0);
}
__device__ __forceinline__ uint32_t pkf16(float a, float b) {
    fp16x2 h = __builtin_amdgcn_cvt_pkrtz(a, b);
    return __builtin_bit_cast(uint32_t, h);
}
__device__ __forceinline__ f16x8 u2f(ull a, ull b) {
    union { ull q[2]; f16x8 v; } u; u.q[0] = a; u.q[1] = b; return u.v;
}
__device__ __forceinline__ int afload(const int* p) {
    return __hip_atomic_load(p, __ATOMIC_ACQUIRE, __HIP_MEMORY_SCOPE_AGENT);
}
__device__ __forceinline__ void afstore(int* p, int v) {
    __hip_atomic_store(p, v, __ATOMIC_RELEASE, __HIP_MEMORY_SCOPE_AGENT);
}
__device__ __forceinline__ void afzero(int* p) {
    __hip_atomic_store(p, 0, __ATOMIC_RELAXED, __HIP_MEMORY_SCOPE_AGENT);
}
__device__ __forceinline__ ull aload(const ull* p) {
    return __hip_atomic_load(p, __ATOMIC_RELAXED, __HIP_MEMORY_SCOPE_AGENT);
}
__device__ __forceinline__ void astore(ull* p, ull v) {
    __hip_atomic_store(p, v, __ATOMIC_RELAXED, __HIP_MEMORY_SCOPE_AGENT);
}

#define REP4(M) M(0)M(1)M(2)M(3)

// A-frag gather (transposed z^T form), scale folded: A[m=16T+l15][k=32F+8q+j]
#define GA(SRC, T, F, SC) (f16x8){ \
  (__fp16)((SC)*(SRC)[(32*(F)+8*quad+0)*256 + 16*(T)+l15]), \
  (__fp16)((SC)*(SRC)[(32*(F)+8*quad+1)*256 + 16*(T)+l15]), \
  (__fp16)((SC)*(SRC)[(32*(F)+8*quad+2)*256 + 16*(T)+l15]), \
  (__fp16)((SC)*(SRC)[(32*(F)+8*quad+3)*256 + 16*(T)+l15]), \
  (__fp16)((SC)*(SRC)[(32*(F)+8*quad+4)*256 + 16*(T)+l15]), \
  (__fp16)((SC)*(SRC)[(32*(F)+8*quad+5)*256 + 16*(T)+l15]), \
  (__fp16)((SC)*(SRC)[(32*(F)+8*quad+6)*256 + 16*(T)+l15]), \
  (__fp16)((SC)*(SRC)[(32*(F)+8*quad+7)*256 + 16*(T)+l15]) }

// Wave uw owns units 16uw..+15; gate G tile T = 4G + uw. -log2e folded into
// i/f/o weights+bias so gates use exp2 directly (saves 24 v_mul/step).
#define DECLW(G) f16x8 uA##G##_0, uA##G##_1, wA##G##_0, wA##G##_1; f32x4 bs##G, wx0s##G;
#define LOADW(G) { \
  const float sc_ = ((G) == 2) ? 1.f : -1.4426950408889634f; \
  const int T_ = 4*(G) + uw; \
  uA##G##_0 = GA(Uw, T_, 0, sc_); uA##G##_1 = GA(Uw, T_, 1, sc_); \
  bs##G = (f32x4){ sc_*bw_[16*T_+4*quad+0], sc_*bw_[16*T_+4*quad+1], \
                   sc_*bw_[16*T_+4*quad+2], sc_*bw_[16*T_+4*quad+3] }; \
  if (lz) { wA##G##_0 = GA(Wsrc, T_, 0, sc_); wA##G##_1 = GA(Wsrc, T_, 1, sc_); } \
  wx0s##G = (f32x4){ sc_*Wx0[16*T_+4*quad+0], sc_*Wx0[16*T_+4*quad+1], \
                     sc_*Wx0[16*T_+4*quad+2], sc_*Wx0[16*T_+4*quad+3] }; }

// One timestep. PX0/PX1 = this step's x-side B-frags (register bank, refilled
// for t+2 after use); PXV = layer-0 scalar x. One barrier/step; flag after
// barrier (barrier's vmcnt drain makes the whole block's stores flag-coverable).
#define STEP(T_, PX0, PX1, PXV) { \
  const int t_ = (T_); \
  const __fp16* hp_ = hb + ((t_+1)&1)*1152 + l15*72 + 8*quad; \
  f16x8 hB0 = *(const f16x8*)hp_; \
  f16x8 hB1 = *(const f16x8*)(hp_ + 32); \
  f32x4 a0, a1, a2, a3; \
  if (lz) { \
    a0 = mfma16(wA0_0, PX0, bs0); a1 = mfma16(wA1_0, PX0, bs1); \
    a2 = mfma16(wA2_0, PX0, bs2); a3 = mfma16(wA3_0, PX0, bs3); \
    a0 = mfma16(wA0_1, PX1, a0);  a1 = mfma16(wA1_1, PX1, a1); \
    a2 = mfma16(wA2_1, PX1, a2);  a3 = mfma16(wA3_1, PX1, a3); \
  } else { \
    f32x4 xv4 = {PXV, PXV, PXV, PXV}; \
    a0 = bs0 + wx0s0*xv4; a1 = bs1 + wx0s1*xv4; \
    a2 = bs2 + wx0s2*xv4; a3 = bs3 + wx0s3*xv4; \
  } \
  /* distance-2 prefetch of t+2 x-side (slack hides L3 latency) */ \
  if (lz) { \
    if (t_ + 2 < TT) { \
      const int need_ = t_ + 3; \
      if (pmin < need_) { do { pmin = afload(pflag); } while (pmin < need_); } \
      const ull* pb_ = wsh + ((size_t)gl_in*NSLOT + ((t_+2)&7))*256 + l15*16; \
      ull q0_ = aload(pb_ + 2*quad),     q1_ = aload(pb_ + 2*quad + 1); \
      ull q2_ = aload(pb_ + 8 + 2*quad), q3_ = aload(pb_ + 8 + 2*quad + 1); \
      PX0 = u2f(q0_, q1_); PX1 = u2f(q2_, q3_); \
    } \
  } else if (t_ + 2 < TT) PXV = xsh[(t_+2)*16 + l15]; \
  a0 = mfma16(uA0_0, hB0, a0); a1 = mfma16(uA1_0, hB0, a1); \
  a2 = mfma16(uA2_0, hB0, a2); a3 = mfma16(uA3_0, hB0, a3); \
  a0 = mfma16(uA0_1, hB1, a0); a1 = mfma16(uA1_1, hB1, a1); \
  a2 = mfma16(uA2_1, hB1, a2); a3 = mfma16(uA3_1, hB1, a3); \
  if (l < 3 && cmin < t_ - 7) { do { cmin = afload(cflag); } while (cmin < t_ - 7); } \
  f32x4 ei_, ef_, eo_; \
  _Pragma("unroll") for (int r_ = 0; r_ < 4; ++r_) { \
    ei_[r_] = __builtin_amdgcn_exp2f(a0[r_]); \
    ef_[r_] = __builtin_amdgcn_exp2f(a1[r_]); \
    eo_[r_] = __builtin_amdgcn_exp2f(a3[r_]); } \
  f32x4 si_, sf_, so_; \
  _Pragma("unroll") for (int r_ = 0; r_ < 4; ++r_) { \
    si_[r_] = __builtin_amdgcn_rcpf(1.0f + ei_[r_]); \
    sf_[r_] = __builtin_amdgcn_rcpf(1.0f + ef_[r_]); \
    so_[r_] = __builtin_amdgcn_rcpf(1.0f + eo_[r_]); } \
  const f32x4 z4_ = {0.f, 0.f, 0.f, 0.f}; \
  f32x4 rg_ = __builtin_elementwise_max(a2, z4_); \
  f32x4 cv_ = sf_*cst + si_*rg_; \
  cst = cv_; \
  f32x4 hv_ = so_*__builtin_elementwise_max(cv_, z4_); \
  u32x2 pk_ = { pkf16(hv_[0], hv_[1]), pkf16(hv_[2], hv_[3]) }; \
  *(u32x2*)(hb + (t_&1)*1152 + l15*72 + uw*16 + 4*quad) = pk_; \
  if (l < 3) astore(wsh + ((size_t)gl_own*NSLOT + (t_&7))*256 + l15*16 + uw*4 + quad, \
                    __builtin_bit_cast(ull, pk_)); \
  if (l == 3 && t_ == TT - 1) hK = hv_; \
  __syncthreads(); \
  if (tid == 0) afstore(myflag, t_ + 1); \
}

// R13 post-mortem: per-block instr stream is batch-invariant -> R12 was already
// issue-bound on its 64 active CUs (active VALU 64% + MFMA 30%). The factor-4:
// one block per (group16, LAYER) = 256 blocks x 4 waves (wave = 16 units, full
// gate set -> in-register gates). Recurrence stays intra-block (LDS); layer
// handoff crosses blocks via d_ws + agent atomics, hidden by dist-2 prefetch.
// 8-slot ring, flag band [3,7], monotone -> deadlock-free; 1 block/CU.
__global__ __launch_bounds__(256)
__attribute__((amdgpu_waves_per_eu(1, 1)))
void lstm_grid(
    const float* __restrict__ x,
    const float* __restrict__ Wx0, const float* __restrict__ U0, const float* __restrict__ b0,
    const float* __restrict__ Wx1, const float* __restrict__ U1, const float* __restrict__ b1,
    const float* __restrict__ Wx2, const float* __restrict__ U2, const float* __restrict__ b2,
    const float* __restrict__ Wx3, const float* __restrict__ U3, const float* __restrict__ b3,
    const float* __restrict__ Wd,  const float* __restrict__ bd,
    float* __restrict__ out, void* __restrict__ ws)
{
    __shared__ __fp16 hb[2 * 16 * 72];     // own-h parity ring [par][row16][unit64 pad72]
    __shared__ float  xsh[TT * 16];        // layer-0 x [t][row]
    __shared__ float  red[4 * 16];

    const int tid  = threadIdx.x;
    const int lane = tid & 63;
    const int l15  = lane & 15;
    const int quad = lane >> 4;
    const int uw   = tid >> 6;             // wave id = unit group
    const int bx   = blockIdx.x;
    const int l    = bx >> 6;              // layer (same-XCD groups: bx, bx+64, ...)
    const int g    = bx & 63;              // batch group
    const bool lz  = (l > 0);
    const int b0i  = g * 16;

    ull* wsh  = (ull*)ws;                                  // h: [(g*3+l)][slot8][256 u64]
    int* wsf  = (int*)((char*)ws + 64 * 3 * NSLOT * 2048); // flags [g*4+l]
    int* myflag = wsf + (g * 4 + l);
    int* pflag  = wsf + (g * 4 + l - 1);
    int* cflag  = wsf + (g * 4 + l + 1);
    const int gl_in  = g * 3 + l - 1;
    const int gl_own = g * 3 + l;          // valid only l<3

    // ---- init ----
    if (tid == 0) afzero(myflag);
    for (int i = tid; i < 1152; i += 256) ((uint32_t*)hb)[i] = 0;
    if (!lz) {
        for (int i = tid; i < 16 * TT; i += 256) {
            int r = i >> 9, t_ = i & (TT - 1);
            xsh[t_ * 16 + r] = x[(b0i + r) * TT + t_];
        }
    }
    const float* Uw   = (l == 0) ? U0 : (l == 1) ? U1 : (l == 2) ? U2 : U3;
    const float* bw_  = (l == 0) ? b0 : (l == 1) ? b1 : (l == 2) ? b2 : b3;
    const float* Wsrc = (l == 1) ? Wx1 : (l == 2) ? Wx2 : (l == 3) ? Wx3 : U0;

    REP4(DECLW)
    REP4(LOADW)

    f32x4 cst = {0, 0, 0, 0};
    f32x4 hK  = {0, 0, 0, 0};
    int pmin = 0, cmin = 0;

    __syncthreads();

    // ---- prologue: fill both prefetch banks (t=0, t=1) ----
    f16x8 xA0 = {}, xA1 = {}, xB0v = {}, xB1v = {};
    float xvA = 0.f, xvB = 0.f;
    if (lz) {
        do { pmin = afload(pflag); } while (pmin < 1);
        {
            const ull* pb = wsh + (size_t)gl_in * NSLOT * 256 + l15 * 16;
            ull q0 = aload(pb + 2*quad),     q1 = aload(pb + 2*quad + 1);
            ull q2 = aload(pb + 8 + 2*quad), q3 = aload(pb + 8 + 2*quad + 1);
            xA0 = u2f(q0, q1); xA1 = u2f(q2, q3);
        }
        if (pmin < 2) { do { pmin = afload(pflag); } while (pmin < 2); }
        {
            const ull* pb = wsh + ((size_t)gl_in * NSLOT + 1) * 256 + l15 * 16;
            ull q0 = aload(pb + 2*quad),     q1 = aload(pb + 2*quad + 1);
            ull q2 = aload(pb + 8 + 2*quad), q3 = aload(pb + 8 + 2*quad + 1);
            xB0v = u2f(q0, q1); xB1v = u2f(q2, q3);
        }
    } else {
        xvA = xsh[l15];
        xvB = xsh[16 + l15];
    }

    for (int t2 = 0; t2 < TT; t2 += 2) {
        STEP(t2,     xA0,  xA1,  xvA)
        STEP(t2 + 1, xB0v, xB1v, xvB)
    }

    // ---- dense epilogue (layer-3 blocks) ----
    if (l == 3) {
        float p = 0.f;
        #pragma unroll
        for (int r = 0; r < 4; ++r)
            p += hK[r] * Wd[16 * uw + 4 * quad + r];
        p += __shfl_xor(p, 16, 64);
        p += __shfl_xor(p, 32, 64);
        if (lane < 16) red[uw * 16 + lane] = p;
        __syncthreads();
        if (uw == 0 && lane < 16)
            out[b0i + lane] = red[lane] + red[16 + lane] + red[32 + lane] + red[48 + lane] + bd[0];
    }
}

extern "C" void kernel_launch(void* const* d_in, const int* in_sizes, int n_in,
                              void* d_out, int out_size, void* d_ws, size_t ws_size,
                              hipStream_t stream) {
    const float* x   = (const float*)d_in[0];
    const float* Wx0 = (const float*)d_in[1];
    const float* U0  = (const float*)d_in[2];
    const float* b0  = (const float*)d_in[3];
    const float* Wx1 = (const float*)d_in[4];
    const float* U1  = (const float*)d_in[5];
    const float* b1  = (const float*)d_in[6];
    const float* Wx2 = (const float*)d_in[7];
    const float* U2  = (const float*)d_in[8];
    const float* b2  = (const float*)d_in[9];
    const float* Wx3 = (const float*)d_in[10];
    const float* U3  = (const float*)d_in[11];
    const float* b3  = (const float*)d_in[12];
    const float* Wd  = (const float*)d_in[13];
    const float* bd  = (const float*)d_in[14];
    float* out = (float*)d_out;

    hipLaunchKernelGGL(lstm_grid, dim3(256), dim3(256), 0, stream,
                       x, Wx0, U0, b0, Wx1, U1, b1, Wx2, U2, b2, Wx3, U3, b3,
                       Wd, bd, out, d_ws);
}